// Round 11
// baseline (197.084 us; speedup 1.0000x reference)
//
#include <hip/hip_runtime.h>

// OSNAP sketch: out[n,f] = sum_d x[n,d] * P[f,d]
// x: [16384,4096] f32. P: [8192,4096] f32, exactly 4 nonzeros (+-0.5) per COLUMN.
// v11 = v10 structure (NR=4, 1024 thr, single barrier, 4 phases x 2 features,
// VGPR<=64 -> 2 blocks/CU) with QUAD-INTERLEAVED swizzled LDS:
//   xs[wq(d)] = {x0[d],x1[d],x2[d],x3[d]} * 0.5,  wq(d) = d ^ ((d>>3)&7)
// -> ONE ds_read_b128 per entry (was 4x b32): LDS-pipe time drops ~4x below the
// HBM floor. Staged by register transpose + balanced ds_write_b128 (8 lanes per
// 4-bank group, exactly). Swizzle baked into packed entries by k_sortpack.

#define D_IN    4096
#define D_FEAT  8192
#define N_TOT   16384
#define CAP     16        // per-row clamp (P(Poisson(2) >= 16) ~ 4e-10 per row)
#define NR      4         // x-rows per gather block
#define PH      2048      // feature stride per phase (1024 threads * 2)
#define OVF_CAP 16384

typedef float f32x4 __attribute__((ext_vector_type(4)));
typedef float f32x2 __attribute__((ext_vector_type(2)));

// ---------------- ws layout (bytes, NO overlaps) ----------------
// 0        row_cnt  int  [D_FEAT]      32768
// 32768    row_ent  int2 [D_FEAT*CAP]  1048576 -> 1081344  (.x=d, .y=bits(val))
// 1081344  ent4     int4 [D_FEAT]      131072  -> 1212416  (4 packed entries/row)
// 1212416  ovf_desc int  [D_FEAT]      32768   -> 1245184  ((start<<5)|extra)
// 1245184  ovf_ents int  [OVF_CAP]     65536   -> 1310720
// 1310720  ovf_base int  [1]           4

// Full-BW streaming scan of P (128MB), binning nonzeros directly into row lists.
__global__ void k_scan(const f32x4* __restrict__ p4,
                       int* __restrict__ row_cnt, int2* __restrict__ row_ent) {
    const long total = (long)D_FEAT * D_IN / 4;
    for (long q = (long)blockIdx.x * blockDim.x + threadIdx.x; q < total;
         q += (long)gridDim.x * blockDim.x) {
        f32x4 v = __builtin_nontemporal_load(&p4[q]);
        long base = q * 4;
        float vals[4] = {v.x, v.y, v.z, v.w};
        #pragma unroll
        for (int c = 0; c < 4; ++c) {
            if (vals[c] != 0.0f) {
                long i = base + c;
                int f = (int)(i >> 12);          // / D_IN
                int d = (int)(i & (D_IN - 1));   // % D_IN
                int slot = atomicAdd(&row_cnt[f], 1);
                if (slot < CAP) row_ent[f * CAP + slot] = make_int2(d, __float_as_int(vals[c]));
            }
        }
    }
}

// Packed entry: byte offset of the swizzled d-quad | sign<<31.
// wq(d) = d ^ ((d>>3)&7); dummy d=D_IN -> wq=4096 -> byte 65536 (zeroed quad).
__device__ __forceinline__ int enc_entry(int d, int valbits) {
    return ((d ^ ((d >> 3) & 7)) << 4) | (int)((unsigned)valbits & 0x80000000u);
}

// Per row f: sort entries by d (distinct -> deterministic), pack first 4 into
// int4 (bit30 of .w = overflow flag), extras -> atomically-allocated compact
// slab. Slab offsets vary run-to-run but per-row entry ORDER doesn't ->
// bitwise-deterministic output.
__global__ void k_sortpack(const int* __restrict__ row_cnt, int2* __restrict__ row_ent,
                           int4* __restrict__ ent4, int* __restrict__ ovf_desc,
                           int* __restrict__ ovf_ents, int* __restrict__ ovf_base) {
    int f = blockIdx.x * blockDim.x + threadIdx.x;
    if (f >= D_FEAT) return;
    int cnt = row_cnt[f];
    if (cnt > CAP) cnt = CAP;
    for (int a = 1; a < cnt; ++a) {
        int2 key = row_ent[f * CAP + a];
        int b = a - 1;
        while (b >= 0) {
            int2 cur = row_ent[f * CAP + b];
            if (cur.x <= key.x) break;
            row_ent[f * CAP + b + 1] = cur;
            --b;
        }
        row_ent[f * CAP + b + 1] = key;
    }
    int e[4];
    #pragma unroll
    for (int j = 0; j < 4; ++j) {
        if (j < cnt) {
            int2 ev = row_ent[f * CAP + j];
            e[j] = enc_entry(ev.x, ev.y);
        } else {
            e[j] = D_IN << 4;   // dummy -> zeroed quad at byte 65536
        }
    }
    int extra = (cnt > 4) ? (cnt - 4) : 0;
    int start = 0;
    if (extra) {
        start = atomicAdd(ovf_base, extra);
        if (start < 0) start = 0;
        if (start > OVF_CAP - CAP) start = OVF_CAP - CAP;   // capacity guard
        for (int j = 0; j < extra; ++j) {
            int2 ev = row_ent[f * CAP + 4 + j];
            ovf_ents[start + j] = enc_entry(ev.x, ev.y);
        }
        e[3] |= 0x40000000;
    }
    ovf_desc[f] = (start << 5) | extra;
    ent4[f] = make_int4(e[0], e[1], e[2], e[3]);
}

// Main gather: one 4-row group per block, single barrier, 2 blocks/CU.
__global__ __launch_bounds__(1024, 8) __attribute__((amdgpu_waves_per_eu(8)))
void k_gather(const float* __restrict__ x,
              const int4* __restrict__ ent4,
              const int* __restrict__ ovf_desc,
              const int* __restrict__ ovf_ents,
              float* __restrict__ out) {
    __shared__ float xs[D_IN * NR + 4];   // 65,552 B: 4096 quads + zero quad
    const int n0 = blockIdx.x * NR;
    const int tid = threadIdx.x;
    const int fb = tid * 2;

    // Prefetch phase-0 structure quads (land alongside the x loads).
    int4 qa0 = ent4[fb + 0];
    int4 qa1 = ent4[fb + 1];

    // Stage: load 4 rows' same-d float4 chunks, pre-scale by 0.5, transpose in
    // registers, write 4 swizzled d-quads via ds_write_b128. For write c, bank
    // group = (4(tid&1)+c) ^ ((tid>>1)&7): exactly 8 lanes per 4-bank group.
    {
        const float* gb = x + (size_t)n0 * D_IN + (tid << 2);
        f32x4 r0 = __builtin_nontemporal_load((const f32x4*)gb);
        f32x4 r1 = __builtin_nontemporal_load((const f32x4*)(gb + D_IN));
        f32x4 r2 = __builtin_nontemporal_load((const f32x4*)(gb + 2 * D_IN));
        f32x4 r3 = __builtin_nontemporal_load((const f32x4*)(gb + 3 * D_IN));
        r0 *= 0.5f; r1 *= 0.5f; r2 *= 0.5f; r3 *= 0.5f;
        char* xw = (char*)xs;
        const int t4 = tid << 2;
        const int swz = (tid >> 1) & 7;
        #pragma unroll
        for (int c = 0; c < 4; ++c) {
            int wq = (t4 + c) ^ swz;
            f32x4 q = {r0[c], r1[c], r2[c], r3[c]};
            *(f32x4*)(xw + (wq << 4)) = q;
        }
    }
    if (tid == 0) {
        f32x4 z = {0.f, 0.f, 0.f, 0.f};
        *(f32x4*)((char*)xs + (D_IN << 4)) = z;   // dummy quad
    }
    __syncthreads();

    const char* xsb = (const char*)xs;
    float* o0 = out + (size_t)n0 * D_FEAT;
    float* o1 = o0 + D_FEAT;
    float* o2 = o1 + D_FEAT;
    float* o3 = o2 + D_FEAT;

    // ENT: one ds_read_b128 gives all 4 rows' x[d]; sign via XOR.
    #define ENT(EE, A0, A1, A2, A3) { \
        int off_ = (EE) & 0x1FFF0; \
        f32x4 q_ = *(const f32x4*)(xsb + off_); \
        unsigned sg_ = (unsigned)(EE) & 0x80000000u; \
        A0 += __uint_as_float(__float_as_uint(q_.x) ^ sg_); \
        A1 += __uint_as_float(__float_as_uint(q_.y) ^ sg_); \
        A2 += __uint_as_float(__float_as_uint(q_.z) ^ sg_); \
        A3 += __uint_as_float(__float_as_uint(q_.w) ^ sg_); }

    // PHASE computes 2 features (quads Q0,Q1) at base FB; f32x2 stores per row.
    #define PHASE(Q0, Q1, FB) { \
        float a00=0,a01=0,a02=0,a03=0, a10=0,a11=0,a12=0,a13=0; \
        ENT(Q0.x,a00,a01,a02,a03) ENT(Q0.y,a00,a01,a02,a03) \
        ENT(Q0.z,a00,a01,a02,a03) ENT(Q0.w,a00,a01,a02,a03) \
        ENT(Q1.x,a10,a11,a12,a13) ENT(Q1.y,a10,a11,a12,a13) \
        ENT(Q1.z,a10,a11,a12,a13) ENT(Q1.w,a10,a11,a12,a13) \
        if ((Q0.w | Q1.w) & 0x40000000) {   /* rare overflow tails */ \
            if (Q0.w & 0x40000000) { int od = ovf_desc[(FB)+0]; int ex = od & 31; \
                const int* oe = ovf_ents + (od >> 5); \
                for (int j = 0; j < ex; ++j) { int ee = oe[j]; ENT(ee,a00,a01,a02,a03) } } \
            if (Q1.w & 0x40000000) { int od = ovf_desc[(FB)+1]; int ex = od & 31; \
                const int* oe = ovf_ents + (od >> 5); \
                for (int j = 0; j < ex; ++j) { int ee = oe[j]; ENT(ee,a10,a11,a12,a13) } } \
        } \
        f32x2 s0_ = {a00, a10}; \
        f32x2 s1_ = {a01, a11}; \
        f32x2 s2_ = {a02, a12}; \
        f32x2 s3_ = {a03, a13}; \
        __builtin_nontemporal_store(s0_, (f32x2*)(o0 + (FB))); \
        __builtin_nontemporal_store(s1_, (f32x2*)(o1 + (FB))); \
        __builtin_nontemporal_store(s2_, (f32x2*)(o2 + (FB))); \
        __builtin_nontemporal_store(s3_, (f32x2*)(o3 + (FB))); }

    // 4 phases; next phase's quads load while current phase computes.
    int4 qb0 = ent4[fb + PH + 0];
    int4 qb1 = ent4[fb + PH + 1];
    PHASE(qa0, qa1, fb)

    qa0 = ent4[fb + 2 * PH + 0];
    qa1 = ent4[fb + 2 * PH + 1];
    PHASE(qb0, qb1, fb + PH)

    qb0 = ent4[fb + 3 * PH + 0];
    qb1 = ent4[fb + 3 * PH + 1];
    PHASE(qa0, qa1, fb + 2 * PH)

    PHASE(qb0, qb1, fb + 3 * PH)

    #undef PHASE
    #undef ENT
}

extern "C" void kernel_launch(void* const* d_in, const int* in_sizes, int n_in,
                              void* d_out, int out_size, void* d_ws, size_t ws_size,
                              hipStream_t stream) {
    const float* x = (const float*)d_in[0];
    const float* P = (const float*)d_in[1];
    float* out = (float*)d_out;

    char* ws = (char*)d_ws;
    int*   row_cnt  = (int*)  (ws + 0);
    int2*  row_ent  = (int2*) (ws + 32768);
    int4*  ent4     = (int4*) (ws + 1081344);
    int*   ovf_desc = (int*)  (ws + 1212416);
    int*   ovf_ents = (int*)  (ws + 1245184);
    int*   ovf_base = (int*)  (ws + 1310720);

    hipMemsetAsync(row_cnt, 0, 32768, stream);
    hipMemsetAsync(ovf_base, 0, 4, stream);
    k_scan    <<<2048, 256, 0, stream>>>((const f32x4*)P, row_cnt, row_ent);
    k_sortpack<<<(D_FEAT + 255) / 256, 256, 0, stream>>>(row_cnt, row_ent, ent4,
                                                         ovf_desc, ovf_ents, ovf_base);
    k_gather  <<<N_TOT / NR, 1024, 0, stream>>>(x, ent4, ovf_desc, ovf_ents, out);
}